// Round 4
// baseline (1421.245 us; speedup 1.0000x reference)
//
#include <hip/hip_runtime.h>

#define SEQ 8192
#define BATCH 16
#define DM 192
#define NROWS (BATCH*SEQ)   // 131072
#define TR 16               // query rows per block
#define HR 20               // rows incl +-2 halo

static __device__ __forceinline__ float dot4(float4 a, float4 b){
  return a.x*b.x + a.y*b.y + a.z*b.z + a.w*b.w;
}

// One block = 16 query rows. Everything (QKV proj, banded attention, out-proj,
// residual, LayerNorm) happens inside the block. Pure f32, no MFMA, no d_ws.
__global__ __launch_bounds__(192) void fused_all(
    const float* __restrict__ x, const float* __restrict__ mask0,
    const float* __restrict__ Wq, const float* __restrict__ bq,
    const float* __restrict__ Wk, const float* __restrict__ bk,
    const float* __restrict__ Wv, const float* __restrict__ bv,
    const float* __restrict__ Wo, const float* __restrict__ bo,
    const float* __restrict__ g, const float* __restrict__ beta,
    float* __restrict__ out)
{
  __shared__ float xs[HR][DM];   // x rows s0-2 .. s0+17 (clamped)
  __shared__ float qs[TR][DM];   // q, then overwritten by ctx
  __shared__ float ks[HR][DM];   // k, then reused as h (pre-LN)
  __shared__ float vs[HR][DM];
  __shared__ float mu_s[TR], rs_s[TR];

  const int t  = threadIdx.x;        // 0..191 = model-dim column
  const int m0 = blockIdx.x * TR;    // global query row base (blocks never straddle batches)
  const int b  = m0 >> 13;           // SEQ = 8192 = 2^13
  const int s0 = m0 & (SEQ - 1);

  // ---- stage x rows (with clamped halo; garbage halos masked later) ----
  #pragma unroll
  for (int j = 0; j < HR; j++) {
    int sl = s0 - 2 + j;
    sl = min(max(sl, 0), SEQ - 1);
    xs[j][t] = x[((size_t)b * SEQ + sl) * DM + t];
  }
  __syncthreads();

  // ---- QKV projection: thread t computes output column t ----
  float aq[TR], ak[HR], av[HR];
  #pragma unroll
  for (int r = 0; r < TR; r++) aq[r] = 0.f;
  #pragma unroll
  for (int j = 0; j < HR; j++) { ak[j] = 0.f; av[j] = 0.f; }

  const float4* wq4 = (const float4*)(Wq + (size_t)t * DM);
  const float4* wk4 = (const float4*)(Wk + (size_t)t * DM);
  const float4* wv4 = (const float4*)(Wv + (size_t)t * DM);

  for (int kc = 0; kc < DM / 4; kc++) {
    float4 wq = wq4[kc], wk = wk4[kc], wv = wv4[kc];
    #pragma unroll
    for (int j = 0; j < HR; j++) {
      float4 xv = *(const float4*)&xs[j][kc * 4];
      ak[j] += dot4(xv, wk);
      av[j] += dot4(xv, wv);
    }
    #pragma unroll
    for (int r = 0; r < TR; r++) {
      float4 xv = *(const float4*)&xs[r + 2][kc * 4];
      aq[r] += dot4(xv, wq);
    }
  }

  const float qscale = 0.28867513459481287f;  // 1/sqrt(12); HF scales bias too
  {
    const float bqv = bq[t], bkv = bk[t], bvv = bv[t];
    #pragma unroll
    for (int r = 0; r < TR; r++) qs[r][t] = (aq[r] + bqv) * qscale;
    #pragma unroll
    for (int j = 0; j < HR; j++) { ks[j][t] = ak[j] + bkv; vs[j][t] = av[j] + bvv; }
  }
  __syncthreads();

  // ---- banded attention: 16 rows x 16 heads = 256 pairs over 192 threads ----
  const float NEGF = -3.402823466e38f;
  const float* mrow = mask0 + (size_t)b * SEQ;
  for (int pp = t; pp < TR * 16; pp += 192) {
    const int lr = pp >> 4, h = pp & 15;
    const int s = s0 + lr;
    const int hb = h * 12;

    float qf[12];
    #pragma unroll
    for (int u = 0; u < 12; u++) qf[u] = qs[lr][hb + u];

    float sc[5];
    #pragma unroll
    for (int d = 0; d < 5; d++) {
      int j = s + d - 2;
      if (j < 0 || j >= SEQ) { sc[d] = -INFINITY; continue; }
      float dot = 0.f;
      #pragma unroll
      for (int u = 0; u < 12; u++) dot += qf[u] * ks[lr + d][hb + u];  // ks[0] = pos s0-2
      sc[d] = dot + ((mrow[j] != 0.0f) ? NEGF : 0.0f);
    }

    float mx = sc[0];
    #pragma unroll
    for (int d = 1; d < 5; d++) mx = fmaxf(mx, sc[d]);
    float e[5], sum = 0.f;
    #pragma unroll
    for (int d = 0; d < 5; d++) { e[d] = __expf(sc[d] - mx); sum += e[d]; }
    const float inv = 1.0f / sum;
    const bool zrow = (mrow[s] < 0.0f);

    float cf[12];
    #pragma unroll
    for (int u = 0; u < 12; u++) cf[u] = 0.f;
    #pragma unroll
    for (int d = 0; d < 5; d++) {
      float p = zrow ? 0.f : e[d] * inv;   // e[d]=0 for invalid j
      #pragma unroll
      for (int u = 0; u < 12; u++) cf[u] += p * vs[lr + d][hb + u];
    }
    #pragma unroll
    for (int u = 0; u < 12; u++) qs[lr][hb + u] = cf[u];  // owner-exclusive
  }
  __syncthreads();

  // ---- out-proj + residual (h into ks, reused) ----
  float ao[TR];
  {
    const float bov = bo[t];
    #pragma unroll
    for (int r = 0; r < TR; r++) ao[r] = bov;
  }
  const float4* wo4 = (const float4*)(Wo + (size_t)t * DM);
  for (int kc = 0; kc < DM / 4; kc++) {
    float4 w = wo4[kc];
    #pragma unroll
    for (int r = 0; r < TR; r++) {
      float4 c = *(const float4*)&qs[r][kc * 4];
      ao[r] += dot4(c, w);
    }
  }
  __syncthreads();   // everyone done reading qs/ks before ks is overwritten
  #pragma unroll
  for (int r = 0; r < TR; r++) ks[r][t] = ao[r] + xs[r + 2][t];
  __syncthreads();

  // ---- LayerNorm ----
  if (t < TR) {
    float s = 0.f, s2 = 0.f;
    for (int k = 0; k < DM; k++) { float v = ks[t][k]; s += v; s2 += v * v; }
    float mu = s * (1.f / DM);
    float var = s2 * (1.f / DM) - mu * mu;
    mu_s[t] = mu;
    rs_s[t] = rsqrtf(var + 1e-12f);
  }
  __syncthreads();

  const float gv = g[t], bv2 = beta[t];
  #pragma unroll
  for (int r = 0; r < TR; r++)
    out[((size_t)m0 + r) * DM + t] = (ks[r][t] - mu_s[r]) * rs_s[r] * gv + bv2;
}

// ------------------------------- launcher ------------------------------------
extern "C" void kernel_launch(void* const* d_in, const int* in_sizes, int n_in,
                              void* d_out, int out_size, void* d_ws, size_t ws_size,
                              hipStream_t stream)
{
  const float* x    = (const float*)d_in[0];
  const float* mask0= (const float*)d_in[1];
  const float* Wq   = (const float*)d_in[2];
  const float* bq   = (const float*)d_in[3];
  const float* Wk   = (const float*)d_in[4];
  const float* bk   = (const float*)d_in[5];
  const float* Wv   = (const float*)d_in[6];
  const float* bv   = (const float*)d_in[7];
  const float* Wo   = (const float*)d_in[8];
  const float* bo   = (const float*)d_in[9];
  const float* lng  = (const float*)d_in[10];
  const float* lnb  = (const float*)d_in[11];
  float* out = (float*)d_out;

  fused_all<<<NROWS / TR, 192, 0, stream>>>(
      x, mask0, Wq, bq, Wk, bk, Wv, bv, Wo, bo, lng, lnb, out);
}

// Round 5
// 716.966 us; speedup vs baseline: 1.9823x; 1.9823x over previous
//
#include <hip/hip_runtime.h>
#include <stdint.h>

#define SEQ 8192
#define BATCH 16
#define DM 192
#define NROWS (BATCH*SEQ)   // 131072

typedef __attribute__((ext_vector_type(8))) short bf16x8;
typedef __attribute__((ext_vector_type(4))) float f32x4;

static __device__ __forceinline__ ushort f2bf(float f){
  uint u = __float_as_uint(f);
  u += 0x7fffu + ((u >> 16) & 1u);
  return (ushort)(u >> 16);
}
// load 8 consecutive f32, round to bf16x8 (A/B fragment)
static __device__ __forceinline__ bf16x8 cvt8(const float* p){
  float4 lo = *(const float4*)p;
  float4 hi = *(const float4*)(p + 4);
  bf16x8 t;
  t[0] = (short)f2bf(lo.x); t[1] = (short)f2bf(lo.y);
  t[2] = (short)f2bf(lo.z); t[3] = (short)f2bf(lo.w);
  t[4] = (short)f2bf(hi.x); t[5] = (short)f2bf(hi.y);
  t[6] = (short)f2bf(hi.z); t[7] = (short)f2bf(hi.w);
  return t;
}
static __device__ __forceinline__ void unpack2(uint u, float& lo, float& hi){
  lo = __uint_as_float(u << 16);
  hi = __uint_as_float(u & 0xffff0000u);
}

// -------- kernel 1: fused QKV projection (MFMA) + banded attention ------------
// 64 query rows per block. 5 m-tiles cover global rows m0-2 .. m0+78; k/v kept
// for rows m0-2..m0+65 (68 rows) in LDS bf16 (52 KB). q staged f32 in d_out,
// then overwritten in place by ctx (owner-exclusive per (row,head) after the
// workgroup barrier). NO d_ws usage anywhere: weights converted on the fly.
__global__ __launch_bounds__(256) void qkv_attn(
    const float* __restrict__ x,
    const float* __restrict__ Wq, const float* __restrict__ bq,
    const float* __restrict__ Wk, const float* __restrict__ bk,
    const float* __restrict__ Wv, const float* __restrict__ bv,
    const float* __restrict__ mask0,
    float* ctxo)
{
  __shared__ ushort ks[68][192];   // rows m0-2 .. m0+65
  __shared__ ushort vs[68][192];

  const int tid  = threadIdx.x;
  const int wave = tid >> 6, lane = tid & 63;
  const int lm   = lane & 15, quad = lane >> 4;
  const int m0   = blockIdx.x * 64;
  const int wbase = wave * 144;   // 4 waves x 144 cols = 576 (q|k|v)

  // per-lane, per-nt weight row pointer + bias + proj (n never straddles 192)
  const float* wrow[9];
  float bias9[9];
  int proj9[9], cin9[9];
  #pragma unroll
  for (int nt = 0; nt < 9; nt++) {
    const int n = wbase + nt * 16 + lm;
    const int proj = n / DM;
    const int cin  = n - proj * DM;
    proj9[nt] = proj; cin9[nt] = cin;
    const float* w = (proj == 0) ? Wq : (proj == 1) ? Wk : Wv;
    wrow[nt] = w + (size_t)cin * DM;
    bias9[nt] = (proj == 0) ? bq[cin] : (proj == 1) ? bk[cin] : bv[cin];
  }

  f32x4 acc[5][9];
  #pragma unroll
  for (int a = 0; a < 5; a++)
    #pragma unroll
    for (int b = 0; b < 9; b++) acc[a][b] = (f32x4){0.f, 0.f, 0.f, 0.f};

  for (int kt = 0; kt < 6; kt++) {
    const int k0 = kt * 32 + quad * 8;
    bf16x8 af[5];
    #pragma unroll
    for (int mt = 0; mt < 5; mt++) {
      int g = m0 - 2 + mt * 16 + lm;          // global row (A m = lane&15)
      g = min(max(g, 0), NROWS - 1);          // clamp; garbage masked later
      af[mt] = cvt8(x + (size_t)g * DM + k0);
    }
    #pragma unroll
    for (int nt = 0; nt < 9; nt++) {
      bf16x8 bfm = cvt8(wrow[nt] + k0);
      #pragma unroll
      for (int mt = 0; mt < 5; mt++)
        acc[mt][nt] = __builtin_amdgcn_mfma_f32_16x16x32_bf16(af[mt], bfm, acc[mt][nt], 0, 0, 0);
    }
  }

  // epilogue. C/D: col=lane&15, row=quad*4+reg. q -> d_out f32; k,v -> LDS bf16
  const float qscale = 0.28867513459481287f;   // 1/sqrt(12); HF scales bias too
  #pragma unroll
  for (int nt = 0; nt < 9; nt++) {
    const int proj = proj9[nt], cin = cin9[nt];
    const float bsv = bias9[nt];
    #pragma unroll
    for (int mt = 0; mt < 5; mt++) {
      #pragma unroll
      for (int r = 0; r < 4; r++) {
        int lrow = mt * 16 + quad * 4 + r;     // 0..79 (global row m0-2+lrow)
        float vv = acc[mt][nt][r] + bsv;
        if (proj == 0) {
          if (lrow >= 2 && lrow < 66)
            ctxo[(size_t)(m0 + lrow - 2) * DM + cin] = vv * qscale;
        } else if (proj == 1) {
          if (lrow < 68) ks[lrow][cin] = f2bf(vv);
        } else {
          if (lrow < 68) vs[lrow][cin] = f2bf(vv);
        }
      }
    }
  }
  __syncthreads();

  // banded attention: 64 rows x 16 heads = 1024 pairs, 4 per thread.
  // ks[0]/vs[0] = global row m0-2; neighbor of (m0+lr) at offset d-2 is lr+d.
  const float NEGF = -3.402823466e38f;
  #pragma unroll
  for (int it = 0; it < 4; it++) {
    const int pair = it * 256 + tid;
    const int h = pair & 15, lr = pair >> 4;
    const int row = m0 + lr;
    const int b = row >> 13, s = row & 8191;
    const float* mrow = mask0 + ((size_t)b << 13);

    float* qp = ctxo + (size_t)row * DM + h * 12;
    float4 q0 = *(const float4*)(qp);
    float4 q1 = *(const float4*)(qp + 4);
    float4 q2 = *(const float4*)(qp + 8);
    float qf[12] = {q0.x, q0.y, q0.z, q0.w, q1.x, q1.y, q1.z, q1.w,
                    q2.x, q2.y, q2.z, q2.w};

    float sc[5];
    #pragma unroll
    for (int d = 0; d < 5; d++) {
      int j = s + d - 2;
      if (j < 0 || j >= SEQ) { sc[d] = -INFINITY; continue; }
      float kf[12];
      const uint2* p = (const uint2*)&ks[lr + d][h * 12];
      uint2 t0 = p[0], t1 = p[1], t2 = p[2];
      unpack2(t0.x, kf[0], kf[1]);  unpack2(t0.y, kf[2], kf[3]);
      unpack2(t1.x, kf[4], kf[5]);  unpack2(t1.y, kf[6], kf[7]);
      unpack2(t2.x, kf[8], kf[9]);  unpack2(t2.y, kf[10], kf[11]);
      float dot = 0.f;
      #pragma unroll
      for (int t = 0; t < 12; t++) dot += qf[t] * kf[t];
      float fm = (mrow[j] != 0.0f) ? NEGF : 0.0f;
      sc[d] = dot + fm;
    }

    float mx = sc[0];
    #pragma unroll
    for (int d = 1; d < 5; d++) mx = fmaxf(mx, sc[d]);
    float e[5], sum = 0.f;
    #pragma unroll
    for (int d = 0; d < 5; d++) { e[d] = __expf(sc[d] - mx); sum += e[d]; }
    float inv = 1.0f / sum;
    const bool zrow = (mrow[s] < 0.0f);

    float cf[12];
    #pragma unroll
    for (int t = 0; t < 12; t++) cf[t] = 0.f;
    #pragma unroll
    for (int d = 0; d < 5; d++) {
      float p = zrow ? 0.f : e[d] * inv;     // e[d]=0 for out-of-range j
      float vf[12];
      const uint2* pv = (const uint2*)&vs[lr + d][h * 12];
      uint2 t0 = pv[0], t1 = pv[1], t2 = pv[2];
      unpack2(t0.x, vf[0], vf[1]);  unpack2(t0.y, vf[2], vf[3]);
      unpack2(t1.x, vf[4], vf[5]);  unpack2(t1.y, vf[6], vf[7]);
      unpack2(t2.x, vf[8], vf[9]);  unpack2(t2.y, vf[10], vf[11]);
      #pragma unroll
      for (int t = 0; t < 12; t++) cf[t] += p * vf[t];
    }

    *(float4*)(qp + 0) = make_float4(cf[0], cf[1], cf[2], cf[3]);
    *(float4*)(qp + 4) = make_float4(cf[4], cf[5], cf[6], cf[7]);
    *(float4*)(qp + 8) = make_float4(cf[8], cf[9], cf[10], cf[11]);
  }
}

// ---------------- kernel 2: out-proj + residual + LayerNorm (in-place) --------
// attn (f32 ctx) lives in the SAME buffer as out; per-block rows are disjoint
// and all ctx reads precede the barriers before the final store. Wo converted
// from f32 on the fly (no d_ws).
__global__ __launch_bounds__(256) void out_ln(
    const float* attn, const float* __restrict__ Wo,
    const float* __restrict__ bo, const float* __restrict__ x,
    const float* __restrict__ g, const float* __restrict__ beta,
    float* out)
{
  __shared__ float hs[64][200];
  __shared__ float red[64][8];
  __shared__ float stats[64][2];

  const int tid  = threadIdx.x;
  const int wave = tid >> 6, lane = tid & 63;
  const int lm   = lane & 15, quad = lane >> 4;
  const int m0   = blockIdx.x * 64;
  const int wbase = wave * 48;

  f32x4 acc[4][3];
  #pragma unroll
  for (int a = 0; a < 4; a++)
    #pragma unroll
    for (int b = 0; b < 3; b++) acc[a][b] = (f32x4){0.f, 0.f, 0.f, 0.f};

  for (int kt = 0; kt < 6; kt++) {
    const int k0 = kt * 32 + quad * 8;
    bf16x8 af[4];
    #pragma unroll
    for (int mt = 0; mt < 4; mt++)
      af[mt] = cvt8(attn + (size_t)(m0 + mt * 16 + lm) * DM + k0);
    #pragma unroll
    for (int nt = 0; nt < 3; nt++) {
      const int n = wbase + nt * 16 + lm;
      bf16x8 bfm = cvt8(Wo + (size_t)n * DM + k0);
      #pragma unroll
      for (int mt = 0; mt < 4; mt++)
        acc[mt][nt] = __builtin_amdgcn_mfma_f32_16x16x32_bf16(af[mt], bfm, acc[mt][nt], 0, 0, 0);
    }
  }

  // h = acc + bo + x  -> LDS
  #pragma unroll
  for (int nt = 0; nt < 3; nt++) {
    const int n = wbase + nt * 16 + lm;
    const float bsv = bo[n];
    #pragma unroll
    for (int mt = 0; mt < 4; mt++) {
      #pragma unroll
      for (int r = 0; r < 4; r++) {
        int rl = mt * 16 + quad * 4 + r;
        hs[rl][n] = acc[mt][nt][r] + bsv + x[(size_t)(m0 + rl) * DM + n];
      }
    }
  }
  __syncthreads();

  // partial reduce: 4 threads per row, 48 cols each
  {
    int row = tid >> 2, seg = tid & 3;
    float s = 0.f, s2 = 0.f;
    #pragma unroll
    for (int c = 0; c < 48; c++) {
      float t = hs[row][seg * 48 + c];
      s += t; s2 += t * t;
    }
    red[row][seg] = s;
    red[row][4 + seg] = s2;
  }
  __syncthreads();
  if (tid < 64) {
    float sum = red[tid][0] + red[tid][1] + red[tid][2] + red[tid][3];
    float sq  = red[tid][4] + red[tid][5] + red[tid][6] + red[tid][7];
    float mu  = sum * (1.f / 192.f);
    float var = sq * (1.f / 192.f) - mu * mu;
    stats[tid][0] = mu;
    stats[tid][1] = rsqrtf(var + 1e-12f);
  }
  __syncthreads();

  // normalize + store (float4)
  #pragma unroll
  for (int it = 0; it < 12; it++) {
    int idx = tid + it * 256;            // 0..3071
    int row = idx / 48, c4 = idx - row * 48;
    float4 hv = *(const float4*)&hs[row][c4 * 4];
    float mu = stats[row][0], rs = stats[row][1];
    float4 gg = *(const float4*)(g + c4 * 4);
    float4 bb = *(const float4*)(beta + c4 * 4);
    float4 o;
    o.x = (hv.x - mu) * rs * gg.x + bb.x;
    o.y = (hv.y - mu) * rs * gg.y + bb.y;
    o.z = (hv.z - mu) * rs * gg.z + bb.z;
    o.w = (hv.w - mu) * rs * gg.w + bb.w;
    *(float4*)(out + (size_t)(m0 + row) * DM + c4 * 4) = o;
  }
}

// ------------------------------- launcher ------------------------------------
extern "C" void kernel_launch(void* const* d_in, const int* in_sizes, int n_in,
                              void* d_out, int out_size, void* d_ws, size_t ws_size,
                              hipStream_t stream)
{
  const float* x    = (const float*)d_in[0];
  const float* mask0= (const float*)d_in[1];
  const float* Wq   = (const float*)d_in[2];
  const float* bq   = (const float*)d_in[3];
  const float* Wk   = (const float*)d_in[4];
  const float* bk   = (const float*)d_in[5];
  const float* Wv   = (const float*)d_in[6];
  const float* bv   = (const float*)d_in[7];
  const float* Wo   = (const float*)d_in[8];
  const float* bo   = (const float*)d_in[9];
  const float* lng  = (const float*)d_in[10];
  const float* lnb  = (const float*)d_in[11];
  float* out = (float*)d_out;

  qkv_attn<<<NROWS / 64, 256, 0, stream>>>(x, Wq, bq, Wk, bk, Wv, bv, mask0, out);
  out_ln<<<NROWS / 64, 256, 0, stream>>>(out, Wo, bo, x, lng, lnb, out);
}